// Round 1
// baseline (291.781 us; speedup 1.0000x reference)
//
#include <hip/hip_runtime.h>
#include <hip/hip_bf16.h>

#define Bdim 32
#define Ndim 4096
#define Cdim 768
#define Kdim 64

typedef float f32x4 __attribute__((ext_vector_type(4)));
typedef short s16x8 __attribute__((ext_vector_type(8)));
typedef __bf16 bf16x8 __attribute__((ext_vector_type(8)));

__device__ __forceinline__ short f2bf(float f) {
  union { float f; unsigned u; } v; v.f = f;
  unsigned r = (v.u + 0x7FFFu + ((v.u >> 16) & 1u)) >> 16;
  return (short)r;
}
__device__ __forceinline__ float bf2f(short s) {
  union { unsigned u; float f; } v; v.u = ((unsigned)(unsigned short)s) << 16;
  return v.f;
}
__device__ __forceinline__ f32x4 MFMA(s16x8 a, s16x8 b, f32x4 c) {
  return __builtin_amdgcn_mfma_f32_16x16x32_bf16(
      __builtin_bit_cast(bf16x8, a), __builtin_bit_cast(bf16x8, b), c, 0, 0, 0);
}

// ---------------- k0: W fp32 -> bf16 ----------------
__global__ void k0_wcvt(const float* __restrict__ W, short* __restrict__ Wb) {
  int idx = blockIdx.x * 256 + threadIdx.x;
  if (idx < Kdim * Cdim) Wb[idx] = f2bf(W[idx]);
}

// ---------------- k1: logits = x @ W^T, stored bf16 in exotic layout ----------------
// Lx[b][n>>3][k][n&7]  (element index: (n>>3)*512 + k*8 + (n&7))
__global__ __launch_bounds__(256) void k1_logits(
    const float* __restrict__ x, const short* __restrict__ Wb,
    short* __restrict__ Lx) {
  const int blk = blockIdx.x;
  const int b = blk >> 6;          // 64 ntiles per batch
  const int ntile = blk & 63;      // 64 rows per tile
  const int tid = threadIdx.x;
  const int w = tid >> 6;          // wave id 0..3 -> rows 16w..16w+15
  const int l = tid & 63;
  const int g = l >> 4, i = l & 15;

  const float* xrow = x + (size_t)(b * Ndim + ntile * 64 + w * 16 + i) * Cdim;
  f32x4 acc[4] = {};

  for (int cs = 0; cs < Cdim / 32; ++cs) {
    const int c0 = cs * 32 + g * 8;
    const float4* ap = (const float4*)(xrow + c0);
    float4 a0 = ap[0];
    float4 a1 = ap[1];
    s16x8 af;
    af[0] = f2bf(a0.x); af[1] = f2bf(a0.y); af[2] = f2bf(a0.z); af[3] = f2bf(a0.w);
    af[4] = f2bf(a1.x); af[5] = f2bf(a1.y); af[6] = f2bf(a1.z); af[7] = f2bf(a1.w);
#pragma unroll
    for (int t = 0; t < 4; ++t) {
      s16x8 bfr = *(const s16x8*)(Wb + (t * 16 + i) * Cdim + c0);
      acc[t] = MFMA(af, bfr, acc[t]);
    }
  }

  short* Lb = Lx + (size_t)b * (Ndim * Kdim);
#pragma unroll
  for (int t = 0; t < 4; ++t) {
#pragma unroll
    for (int r = 0; r < 4; ++r) {
      int n = ntile * 64 + w * 16 + g * 4 + r;  // D row = 4*(l>>4)+reg
      int k = t * 16 + i;                       // D col = l&15
      Lb[(n >> 3) * 512 + k * 8 + (n & 7)] = f2bf(acc[t][r]);
    }
  }
}

// ---------------- k2: per-(b,k) max and sum-exp over n ----------------
__global__ __launch_bounds__(256) void k2_stats(
    const short* __restrict__ Lx, float* __restrict__ mout,
    float* __restrict__ invd) {
  const int b = blockIdx.x >> 6, k = blockIdx.x & 63;
  const short* Lb = Lx + (size_t)b * (Ndim * Kdim);
  const int t = threadIdx.x;

  float vals[16];
#pragma unroll
  for (int h = 0; h < 2; ++h) {
    s16x8 v = *(const s16x8*)(Lb + (size_t)(t + h * 256) * 512 + k * 8);
#pragma unroll
    for (int e = 0; e < 8; ++e) vals[h * 8 + e] = bf2f(v[e]);
  }
  float mx = vals[0];
#pragma unroll
  for (int e = 1; e < 16; ++e) mx = fmaxf(mx, vals[e]);
  for (int off = 32; off > 0; off >>= 1) mx = fmaxf(mx, __shfl_xor(mx, off));

  __shared__ float red[4];
  if ((t & 63) == 0) red[t >> 6] = mx;
  __syncthreads();
  mx = fmaxf(fmaxf(red[0], red[1]), fmaxf(red[2], red[3]));

  float s = 0.f;
#pragma unroll
  for (int e = 0; e < 16; ++e) s += __expf(vals[e] - mx);
  for (int off = 32; off > 0; off >>= 1) s += __shfl_xor(s, off);
  __syncthreads();
  if ((t & 63) == 0) red[t >> 6] = s;
  __syncthreads();
  if (t == 0) {
    float tot = red[0] + red[1] + red[2] + red[3];
    mout[blockIdx.x] = mx;
    invd[blockIdx.x] = 1.f / tot;
  }
}

// ---------------- k3: out[b,k,c] = (1/denom) * sum_n exp(s-m) * x[b,n,c] ----------------
#define CT 48    // c-columns per block (3 MFMA n-tiles of 16)
#define NCH 128  // n rows staged per chunk
#define PITCH 56 // LDS row pitch in elements (16B-aligned writes, ~2-4 way read conflict)
__global__ __launch_bounds__(256) void k3_tokens(
    const float* __restrict__ x, const short* __restrict__ Lx,
    const float* __restrict__ mv, const float* __restrict__ invd,
    float* __restrict__ out) {
  __shared__ short xs[NCH * PITCH];
  const int blk = blockIdx.x;
  const int b = blk >> 4;   // 16 c-tiles per batch
  const int ct = blk & 15;
  const int tid = threadIdx.x;
  const int w = tid >> 6, l = tid & 63, g = l >> 4, i = l & 15;

  const float* xb = x + (size_t)b * Ndim * Cdim;
  const short* Lb = Lx + (size_t)b * (Ndim * Kdim);
  const float mk = mv[b * Kdim + w * 16 + i];  // A row k = w*16 + (l&15)

  f32x4 acc[3] = {};

  for (int ch = 0; ch < Ndim / NCH; ++ch) {
    const int n0 = ch * NCH;
    __syncthreads();  // previous chunk's reads complete before overwrite
    // stage x[n0..n0+127][ct*48 .. +47] fp32 -> bf16 LDS
#pragma unroll
    for (int uu = 0; uu < 3; ++uu) {
      int u = tid + uu * 256;       // 768 units of 8 elements
      int n = u / 6, c8 = u % 6;
      const float4* src =
          (const float4*)(xb + (size_t)(n0 + n) * Cdim + ct * CT + c8 * 8);
      float4 v0 = src[0];
      float4 v1 = src[1];
      s16x8 sv;
      sv[0] = f2bf(v0.x); sv[1] = f2bf(v0.y); sv[2] = f2bf(v0.z); sv[3] = f2bf(v0.w);
      sv[4] = f2bf(v1.x); sv[5] = f2bf(v1.y); sv[6] = f2bf(v1.z); sv[7] = f2bf(v1.w);
      *(s16x8*)(xs + n * PITCH + c8 * 8) = sv;
    }
    __syncthreads();
#pragma unroll
    for (int ns = 0; ns < 4; ++ns) {
      const int nb = n0 + ns * 32;
      // A fragment: P[k = w*16+i][n = nb + 8g + e] from exotic logits (contiguous)
      s16x8 lv = *(const s16x8*)(Lb + (size_t)((nb >> 3) + g) * 512 + (w * 16 + i) * 8);
      s16x8 af;
#pragma unroll
      for (int e = 0; e < 8; ++e) af[e] = f2bf(__expf(bf2f(lv[e]) - mk));
#pragma unroll
      for (int cs = 0; cs < 3; ++cs) {
        // B fragment: x[n = nb + 8g + e][c = ct*48 + cs*16 + i]
        s16x8 bfr;
#pragma unroll
        for (int e = 0; e < 8; ++e)
          bfr[e] = xs[(ns * 32 + g * 8 + e) * PITCH + cs * 16 + i];
        acc[cs] = MFMA(af, bfr, acc[cs]);
      }
    }
  }

  float* ob = out + (size_t)b * Kdim * Cdim;
#pragma unroll
  for (int r = 0; r < 4; ++r) {
    const int k = w * 16 + g * 4 + r;  // D row
    const float sc = invd[b * Kdim + k];
#pragma unroll
    for (int cs = 0; cs < 3; ++cs) {
      ob[(size_t)k * Cdim + ct * CT + cs * 16 + i] = acc[cs][r] * sc;  // D col = i
    }
  }
}

extern "C" void kernel_launch(void* const* d_in, const int* in_sizes, int n_in,
                              void* d_out, int out_size, void* d_ws, size_t ws_size,
                              hipStream_t stream) {
  const float* x = (const float*)d_in[0];
  const float* W = (const float*)d_in[1];
  float* out = (float*)d_out;
  char* ws = (char*)d_ws;

  short* Wb = (short*)ws;                                   // 96 KB
  short* Lx = (short*)(ws + (1 << 17));                     // 16 MB bf16 logits
  float* mv = (float*)(ws + (1 << 17) + Bdim * Ndim * Kdim * 2);
  float* iv = mv + Bdim * Kdim;

  hipLaunchKernelGGL(k0_wcvt, dim3(192), dim3(256), 0, stream, W, Wb);
  hipLaunchKernelGGL(k1_logits, dim3(Bdim * 64), dim3(256), 0, stream, x, Wb, Lx);
  hipLaunchKernelGGL(k2_stats, dim3(Bdim * Kdim), dim3(256), 0, stream, Lx, mv, iv);
  hipLaunchKernelGGL(k3_tokens, dim3(Bdim * 16), dim3(256), 0, stream, x, Lx, mv, iv, out);
}

// Round 2
// 268.146 us; speedup vs baseline: 1.0881x; 1.0881x over previous
//
#include <hip/hip_runtime.h>
#include <hip/hip_bf16.h>

#define Bdim 32
#define Ndim 4096
#define Cdim 768
#define Kdim 64

typedef float f32x4 __attribute__((ext_vector_type(4)));
typedef short s16x8 __attribute__((ext_vector_type(8)));
typedef __bf16 bf16x8 __attribute__((ext_vector_type(8)));

__device__ __forceinline__ short f2bf(float f) {
  return __builtin_bit_cast(short, (__bf16)f);   // hw RNE cvt, 1 VALU op
}
__device__ __forceinline__ float bf2f(short s) {
  return (float)__builtin_bit_cast(__bf16, s);
}
__device__ __forceinline__ f32x4 MFMA(s16x8 a, s16x8 b, f32x4 c) {
  return __builtin_amdgcn_mfma_f32_16x16x32_bf16(
      __builtin_bit_cast(bf16x8, a), __builtin_bit_cast(bf16x8, b), c, 0, 0, 0);
}

// ---------------- k0: W fp32 -> bf16 ----------------
__global__ void k0_wcvt(const float* __restrict__ W, short* __restrict__ Wb) {
  int idx = blockIdx.x * 256 + threadIdx.x;
  if (idx < Kdim * Cdim) Wb[idx] = f2bf(W[idx]);
}

// ---------------- k1: logits = x @ W^T, stored bf16 in exotic layout ----------------
// Lx[b][n>>3][k][n&7]  (element index: (n>>3)*512 + k*8 + (n&7))
__global__ __launch_bounds__(256) void k1_logits(
    const float* __restrict__ x, const short* __restrict__ Wb,
    short* __restrict__ Lx) {
  const int blk = blockIdx.x;
  const int b = blk >> 6;          // 64 ntiles per batch
  const int ntile = blk & 63;      // 64 rows per tile
  const int tid = threadIdx.x;
  const int w = tid >> 6;          // wave id 0..3 -> rows 16w..16w+15
  const int l = tid & 63;
  const int g = l >> 4, i = l & 15;

  const float* xrow = x + (size_t)(b * Ndim + ntile * 64 + w * 16 + i) * Cdim;
  f32x4 acc[4] = {};

  for (int cs = 0; cs < Cdim / 32; ++cs) {
    const int c0 = cs * 32 + g * 8;
    const float4* ap = (const float4*)(xrow + c0);
    float4 a0 = ap[0];
    float4 a1 = ap[1];
    s16x8 af;
    af[0] = f2bf(a0.x); af[1] = f2bf(a0.y); af[2] = f2bf(a0.z); af[3] = f2bf(a0.w);
    af[4] = f2bf(a1.x); af[5] = f2bf(a1.y); af[6] = f2bf(a1.z); af[7] = f2bf(a1.w);
#pragma unroll
    for (int t = 0; t < 4; ++t) {
      s16x8 bfr = *(const s16x8*)(Wb + (t * 16 + i) * Cdim + c0);
      acc[t] = MFMA(af, bfr, acc[t]);
    }
  }

  short* Lb = Lx + (size_t)b * (Ndim * Kdim);
#pragma unroll
  for (int t = 0; t < 4; ++t) {
#pragma unroll
    for (int r = 0; r < 4; ++r) {
      int n = ntile * 64 + w * 16 + g * 4 + r;  // D row = 4*(l>>4)+reg
      int k = t * 16 + i;                       // D col = l&15
      Lb[(n >> 3) * 512 + k * 8 + (n & 7)] = f2bf(acc[t][r]);
    }
  }
}

// ---------------- k2a: partial (max, sumexp) per (b, quarter, k) ----------------
// grid: 128 blocks = (b, q). thread t: k = t&63 (lane), sub = t>>6 (wave).
// Each thread scans 256 n (32 x s16x8), fully coalesced (1KB per wave instr).
__global__ __launch_bounds__(256) void k2a_partial(
    const short* __restrict__ Lx, float* __restrict__ pm,
    float* __restrict__ ps) {
  const int b = blockIdx.x >> 2, q = blockIdx.x & 3;
  const int t = threadIdx.x;
  const int k = t & 63, sub = t >> 6;
  const short* Lb = Lx + (size_t)b * (Ndim * Kdim);

  float m = -1e30f, s = 0.f;
  for (int it = 0; it < 32; ++it) {
    const int n8 = q * 128 + sub * 32 + it;  // n-block of 8
    s16x8 v = *(const s16x8*)(Lb + (size_t)n8 * 512 + k * 8);
    float vals[8];
#pragma unroll
    for (int e = 0; e < 8; ++e) vals[e] = bf2f(v[e]);
    float lm = vals[0];
#pragma unroll
    for (int e = 1; e < 8; ++e) lm = fmaxf(lm, vals[e]);
    if (lm > m) { s *= __expf(m - lm); m = lm; }
#pragma unroll
    for (int e = 0; e < 8; ++e) s += __expf(vals[e] - m);
  }

  __shared__ float sm[4][64], ss[4][64];
  sm[sub][k] = m;
  ss[sub][k] = s;
  __syncthreads();
  if (t < 64) {
    float M = sm[0][t];
#pragma unroll
    for (int u = 1; u < 4; ++u) M = fmaxf(M, sm[u][t]);
    float S = 0.f;
#pragma unroll
    for (int u = 0; u < 4; ++u) S += ss[u][t] * __expf(sm[u][t] - M);
    pm[(size_t)blockIdx.x * 64 + t] = M;
    ps[(size_t)blockIdx.x * 64 + t] = S;
  }
}

// ---------------- k2b: combine 4 quarters -> m, 1/denom ----------------
__global__ __launch_bounds__(256) void k2b_combine(
    const float* __restrict__ pm, const float* __restrict__ ps,
    float* __restrict__ mout, float* __restrict__ invd) {
  const int idx = blockIdx.x * 256 + threadIdx.x;  // = b*64 + k
  if (idx >= Bdim * Kdim) return;
  const int b = idx >> 6, k = idx & 63;
  float M = -1e30f;
#pragma unroll
  for (int q = 0; q < 4; ++q) M = fmaxf(M, pm[(b * 4 + q) * 64 + k]);
  float S = 0.f;
#pragma unroll
  for (int q = 0; q < 4; ++q)
    S += ps[(b * 4 + q) * 64 + k] * __expf(pm[(b * 4 + q) * 64 + k] - M);
  mout[idx] = M;
  invd[idx] = 1.f / S;
}

// ---------------- k3: out[b,k,c] = (1/denom) * sum_n exp(s-m) * x[b,n,c] ----------------
// x staged TRANSPOSED in LDS: xs_t[c][n], 256B rows, XOR-swizzled so both the
// scalar transposing writes and the vector (b128) fragment reads are conflict-lite.
#define CT 48    // c-columns per block (3 MFMA c-tiles of 16)
#define NCH 128  // n rows staged per chunk
__device__ __forceinline__ int swz(int c) {
  return ((((c >> 3) ^ c) & 7) << 4);  // byte-XOR within a 256B row
}
__global__ __launch_bounds__(256) void k3_tokens(
    const float* __restrict__ x, const short* __restrict__ Lx,
    const float* __restrict__ mv, const float* __restrict__ invd,
    float* __restrict__ out) {
  __shared__ short xs[CT * 128];  // CT rows x 256 bytes
  char* xsb = (char*)xs;
  const int blk = blockIdx.x;
  const int b = blk >> 4;   // 16 c-tiles per batch
  const int ct = blk & 15;
  const int tid = threadIdx.x;
  const int w = tid >> 6, l = tid & 63, g = l >> 4, i = l & 15;

  const float* xb = x + (size_t)b * Ndim * Cdim;
  const short* Lb = Lx + (size_t)b * (Ndim * Kdim);
  const float mk = mv[b * Kdim + w * 16 + i];  // A row k = w*16 + (l&15)

  f32x4 acc[3] = {};

  for (int ch = 0; ch < Ndim / NCH; ++ch) {
    const int n0 = ch * NCH;
    __syncthreads();  // previous chunk's reads complete before overwrite
    // stage x[n0..n0+127][ct*48 .. +47] fp32 -> bf16, transposed into xs_t[c][n]
#pragma unroll
    for (int uu = 0; uu < 3; ++uu) {
      int u = tid + uu * 256;       // 768 units of 8 elements
      int n = u / 6, c8 = u % 6;
      const float4* src =
          (const float4*)(xb + (size_t)(n0 + n) * Cdim + ct * CT + c8 * 8);
      float4 v0 = src[0];
      float4 v1 = src[1];
      float fv[8] = {v0.x, v0.y, v0.z, v0.w, v1.x, v1.y, v1.z, v1.w};
#pragma unroll
      for (int e = 0; e < 8; ++e) {
        int c = c8 * 8 + e;
        *(short*)(xsb + c * 256 + ((2 * n) ^ swz(c))) = f2bf(fv[e]);
      }
    }
    __syncthreads();
#pragma unroll
    for (int ns = 0; ns < 4; ++ns) {
      const int nb = n0 + ns * 32;
      // A fragment: P[k = w*16+i][n = nb + 8g + e] from exotic logits (contiguous)
      s16x8 lv = *(const s16x8*)(Lb + (size_t)((nb >> 3) + g) * 512 + (w * 16 + i) * 8);
      s16x8 af;
#pragma unroll
      for (int e = 0; e < 8; ++e) af[e] = f2bf(__expf(bf2f(lv[e]) - mk));
#pragma unroll
      for (int cs = 0; cs < 3; ++cs) {
        // B fragment: xs_t[c = cs*16+i][n = ns*32 + 8g .. +7] -> one b128 read
        const int c = cs * 16 + i;
        s16x8 bfr = *(const s16x8*)(xsb + c * 256 + ((ns * 64 + g * 16) ^ swz(c)));
        acc[cs] = MFMA(af, bfr, acc[cs]);
      }
    }
  }

  float* ob = out + (size_t)b * Kdim * Cdim;
#pragma unroll
  for (int r = 0; r < 4; ++r) {
    const int k = w * 16 + g * 4 + r;  // D row
    const float sc = invd[b * Kdim + k];
#pragma unroll
    for (int cs = 0; cs < 3; ++cs) {
      ob[(size_t)k * Cdim + ct * CT + cs * 16 + i] = acc[cs][r] * sc;  // D col = i
    }
  }
}

extern "C" void kernel_launch(void* const* d_in, const int* in_sizes, int n_in,
                              void* d_out, int out_size, void* d_ws, size_t ws_size,
                              hipStream_t stream) {
  const float* x = (const float*)d_in[0];
  const float* W = (const float*)d_in[1];
  float* out = (float*)d_out;
  char* ws = (char*)d_ws;

  short* Wb = (short*)ws;                                   // 96 KB (pad 128K)
  short* Lx = (short*)(ws + (1 << 17));                     // 32 MB bf16 logits
  char* after = ws + (1 << 17) + (size_t)Bdim * Ndim * Kdim * 2;
  float* pm = (float*)after;                                // 128*64 partial max
  float* psum = pm + 128 * 64;                              // 128*64 partial sum
  float* mv = psum + 128 * 64;                              // 2048 max
  float* iv = mv + Bdim * Kdim;                             // 2048 inv-denom

  hipLaunchKernelGGL(k0_wcvt, dim3(192), dim3(256), 0, stream, W, Wb);
  hipLaunchKernelGGL(k1_logits, dim3(Bdim * 64), dim3(256), 0, stream, x, Wb, Lx);
  hipLaunchKernelGGL(k2a_partial, dim3(Bdim * 4), dim3(256), 0, stream, Lx, pm, psum);
  hipLaunchKernelGGL(k2b_combine, dim3(8), dim3(256), 0, stream, pm, psum, mv, iv);
  hipLaunchKernelGGL(k3_tokens, dim3(Bdim * 16), dim3(256), 0, stream, x, Lx, mv, iv, out);
}

// Round 3
// 261.577 us; speedup vs baseline: 1.1155x; 1.0251x over previous
//
#include <hip/hip_runtime.h>
#include <hip/hip_bf16.h>

#define Bdim 32
#define Ndim 4096
#define Cdim 768
#define Kdim 64

typedef float f32x4 __attribute__((ext_vector_type(4)));
typedef short s16x8 __attribute__((ext_vector_type(8)));
typedef __bf16 bf16x8 __attribute__((ext_vector_type(8)));

__device__ __forceinline__ short f2bf(float f) {
  return __builtin_bit_cast(short, (__bf16)f);   // hw RNE cvt
}
__device__ __forceinline__ float bf2f(short s) {
  return (float)__builtin_bit_cast(__bf16, s);
}
__device__ __forceinline__ f32x4 MFMA(s16x8 a, s16x8 b, f32x4 c) {
  return __builtin_amdgcn_mfma_f32_16x16x32_bf16(
      __builtin_bit_cast(bf16x8, a), __builtin_bit_cast(bf16x8, b), c, 0, 0, 0);
}

// ---------------- k0: W fp32 -> bf16 ----------------
__global__ void k0_wcvt(const float* __restrict__ W, short* __restrict__ Wb) {
  int idx = blockIdx.x * 256 + threadIdx.x;
  if (idx < Kdim * Cdim) Wb[idx] = f2bf(W[idx]);
}

// ---------------- k1: logits = x @ W^T (exotic layout) + fused per-tile stats ----
// Lx[b][n>>3][k][n&7]; pm/ps[b][ntile][k] = per-64-row-tile max / sum-exp
__global__ __launch_bounds__(256) void k1_logits(
    const float* __restrict__ x, const short* __restrict__ Wb,
    short* __restrict__ Lx, float* __restrict__ pm, float* __restrict__ ps) {
  const int blk = blockIdx.x;
  const int b = blk >> 6;          // 64 ntiles per batch
  const int ntile = blk & 63;      // 64 rows per tile
  const int tid = threadIdx.x;
  const int w = tid >> 6;          // wave id 0..3 -> rows 16w..16w+15
  const int l = tid & 63;
  const int g = l >> 4, i = l & 15;

  const float* xrow = x + (size_t)(b * Ndim + ntile * 64 + w * 16 + i) * Cdim;
  f32x4 acc[4] = {};

  for (int cs = 0; cs < Cdim / 32; ++cs) {
    const int c0 = cs * 32 + g * 8;
    const float4* ap = (const float4*)(xrow + c0);
    float4 a0 = ap[0];
    float4 a1 = ap[1];
    s16x8 af;
    af[0] = f2bf(a0.x); af[1] = f2bf(a0.y); af[2] = f2bf(a0.z); af[3] = f2bf(a0.w);
    af[4] = f2bf(a1.x); af[5] = f2bf(a1.y); af[6] = f2bf(a1.z); af[7] = f2bf(a1.w);
#pragma unroll
    for (int t = 0; t < 4; ++t) {
      s16x8 bfr = *(const s16x8*)(Wb + (t * 16 + i) * Cdim + c0);
      acc[t] = MFMA(af, bfr, acc[t]);
    }
  }

  // store logits (rounded) + keep rounded values for stats
  short* Lb = Lx + (size_t)b * (Ndim * Kdim);
  float rnd[4][4];
#pragma unroll
  for (int t = 0; t < 4; ++t) {
#pragma unroll
    for (int r = 0; r < 4; ++r) {
      int n = ntile * 64 + w * 16 + g * 4 + r;  // D row = 4*(l>>4)+reg
      int k = t * 16 + i;                       // D col = l&15
      short hv = f2bf(acc[t][r]);
      Lb[(n >> 3) * 512 + k * 8 + (n & 7)] = hv;
      rnd[t][r] = bf2f(hv);
    }
  }

  // ---- fused per-tile (max, sum-exp) over the tile's 64 n for each k ----
  __shared__ float rm[4][4][16], rs[4][4][16];  // [w][t][i]
  float tm[4];
#pragma unroll
  for (int t = 0; t < 4; ++t) {
    tm[t] = fmaxf(fmaxf(rnd[t][0], rnd[t][1]), fmaxf(rnd[t][2], rnd[t][3]));
    tm[t] = fmaxf(tm[t], __shfl_xor(tm[t], 16));
    tm[t] = fmaxf(tm[t], __shfl_xor(tm[t], 32));
  }
  if (g == 0) {
#pragma unroll
    for (int t = 0; t < 4; ++t) rm[w][t][i] = tm[t];
  }
  __syncthreads();
  float M[4], sv[4];
#pragma unroll
  for (int t = 0; t < 4; ++t) {
    M[t] = fmaxf(fmaxf(rm[0][t][i], rm[1][t][i]), fmaxf(rm[2][t][i], rm[3][t][i]));
    sv[t] = __expf(rnd[t][0] - M[t]) + __expf(rnd[t][1] - M[t]) +
            __expf(rnd[t][2] - M[t]) + __expf(rnd[t][3] - M[t]);
    sv[t] += __shfl_xor(sv[t], 16);
    sv[t] += __shfl_xor(sv[t], 32);
  }
  if (g == 0) {
#pragma unroll
    for (int t = 0; t < 4; ++t) rs[w][t][i] = sv[t];
  }
  __syncthreads();
  if (w == 0 && g == 0) {
#pragma unroll
    for (int t = 0; t < 4; ++t) {
      float S = rs[0][t][i] + rs[1][t][i] + rs[2][t][i] + rs[3][t][i];
      pm[((size_t)b * 64 + ntile) * 64 + t * 16 + i] = M[t];
      ps[((size_t)b * 64 + ntile) * 64 + t * 16 + i] = S;
    }
  }
}

// ---------------- k2b: combine 64 tile-partials -> m, 1/denom ----------------
__global__ __launch_bounds__(256) void k2b_combine(
    const float* __restrict__ pm, const float* __restrict__ ps,
    float* __restrict__ mout, float* __restrict__ invd) {
  const int idx = blockIdx.x * 256 + threadIdx.x;  // = b*64 + k
  const int b = idx >> 6, k = idx & 63;
  float am[64];
#pragma unroll 64
  for (int nt = 0; nt < 64; ++nt) am[nt] = pm[((size_t)b * 64 + nt) * 64 + k];
  float M = am[0];
#pragma unroll 64
  for (int nt = 1; nt < 64; ++nt) M = fmaxf(M, am[nt]);
  float S = 0.f;
#pragma unroll 64
  for (int nt = 0; nt < 64; ++nt)
    S += ps[((size_t)b * 64 + nt) * 64 + k] * __expf(am[nt] - M);
  mout[idx] = M;
  invd[idx] = 1.f / S;
}

// ---------------- k3: out[b,k,c] = (1/denom) * sum_n exp(s-m) * x[b,n,c] ----------------
// x staged TRANSPOSED in LDS (xs_t[c][n], XOR-swizzled). Software-pipelined:
// chunk t+1's global loads (x + logits) issue before chunk t's MFMA phase (T14).
#define CT 48    // c-columns per block
#define NCH 128  // n rows staged per chunk
__device__ __forceinline__ int swz(int c) {
  return ((((c >> 3) ^ c) & 7) << 4);  // byte-XOR within a 256B row
}
__global__ __launch_bounds__(256) void k3_tokens(
    const float* __restrict__ x, const short* __restrict__ Lx,
    const float* __restrict__ mv, const float* __restrict__ invd,
    float* __restrict__ out) {
  __shared__ short xs[CT * 128];  // CT rows x 256 bytes
  char* xsb = (char*)xs;
  const int blk = blockIdx.x;
  const int b = blk >> 4;   // 16 c-tiles per batch
  const int ct = blk & 15;
  const int tid = threadIdx.x;
  const int w = tid >> 6, l = tid & 63, g = l >> 4, i = l & 15;

  const float* xb = x + (size_t)b * Ndim * Cdim;
  const short* Lb = Lx + (size_t)b * (Ndim * Kdim);
  const float mk = mv[b * Kdim + w * 16 + i];  // A row k = w*16 + (l&15)

  const int un = tid / 6 + ((tid % 6) > (255 % 6) ? 0 : 0); // (placeholder, unused)
  (void)un;

  f32x4 acc[3] = {};

#define LOADX(ch, buf)                                                        \
  do {                                                                        \
    const int n0_ = (ch) * NCH;                                               \
    _Pragma("unroll") for (int uu = 0; uu < 3; ++uu) {                        \
      int u_ = tid + uu * 256;                                                \
      int n_ = u_ / 6, c8_ = u_ % 6;                                          \
      const float4* src_ =                                                    \
          (const float4*)(xb + (size_t)(n0_ + n_) * Cdim + ct * CT + c8_ * 8);\
      buf[uu][0] = src_[0];                                                   \
      buf[uu][1] = src_[1];                                                   \
    }                                                                         \
  } while (0)

#define LOADL(ch, lvb)                                                        \
  do {                                                                        \
    const int nb8_ = (ch) * 16;                                               \
    _Pragma("unroll") for (int ns = 0; ns < 4; ++ns) {                        \
      lvb[ns] = *(const s16x8*)(Lb + (size_t)(nb8_ + ns * 4 + g) * 512 +      \
                                (w * 16 + i) * 8);                            \
    }                                                                         \
  } while (0)

#define STORELDS(buf)                                                         \
  do {                                                                        \
    _Pragma("unroll") for (int uu = 0; uu < 3; ++uu) {                        \
      int u_ = tid + uu * 256;                                                \
      int n_ = u_ / 6, c8_ = u_ % 6;                                          \
      float4 v0_ = buf[uu][0], v1_ = buf[uu][1];                              \
      float fv_[8] = {v0_.x, v0_.y, v0_.z, v0_.w, v1_.x, v1_.y, v1_.z, v1_.w};\
      _Pragma("unroll") for (int e = 0; e < 8; ++e) {                         \
        int c_ = c8_ * 8 + e;                                                 \
        *(short*)(xsb + c_ * 256 + ((2 * n_) ^ swz(c_))) = f2bf(fv_[e]);      \
      }                                                                       \
    }                                                                         \
  } while (0)

#define COMPUTE(lvb)                                                          \
  do {                                                                        \
    _Pragma("unroll") for (int ns = 0; ns < 4; ++ns) {                        \
      s16x8 af_;                                                              \
      _Pragma("unroll") for (int e = 0; e < 8; ++e)                           \
          af_[e] = f2bf(__expf(bf2f(lvb[ns][e]) - mk));                       \
      _Pragma("unroll") for (int cs = 0; cs < 3; ++cs) {                      \
        const int c_ = cs * 16 + i;                                           \
        s16x8 bfr_ = *(const s16x8*)(xsb + c_ * 256 +                         \
                                     ((ns * 64 + g * 16) ^ swz(c_)));         \
        acc[cs] = MFMA(af_, bfr_, acc[cs]);                                   \
      }                                                                       \
    }                                                                         \
  } while (0)

  float4 stA[3][2], stB[3][2];
  s16x8 lvA[4], lvB[4];

  LOADX(0, stA);
  LOADL(0, lvA);
  for (int ch = 0; ch < 32; ch += 2) {
    // even sub-iteration: consume A, prefetch B
    __syncthreads();          // prior chunk's LDS reads complete
    STORELDS(stA);
    LOADX(ch + 1, stB);       // next chunk x -> regs (in flight during COMPUTE)
    LOADL(ch + 1, lvB);       // next chunk logits -> regs
    __syncthreads();          // LDS tile ready
    COMPUTE(lvA);
    // odd sub-iteration: consume B, prefetch A
    __syncthreads();
    STORELDS(stB);
    if (ch + 2 < 32) {
      LOADX(ch + 2, stA);
      LOADL(ch + 2, lvA);
    }
    __syncthreads();
    COMPUTE(lvB);
  }

  float* ob = out + (size_t)b * Kdim * Cdim;
#pragma unroll
  for (int r = 0; r < 4; ++r) {
    const int k = w * 16 + g * 4 + r;  // D row
    const float sc = invd[b * Kdim + k];
#pragma unroll
    for (int cs = 0; cs < 3; ++cs) {
      ob[(size_t)k * Cdim + ct * CT + cs * 16 + i] = acc[cs][r] * sc;  // D col = i
    }
  }
#undef LOADX
#undef LOADL
#undef STORELDS
#undef COMPUTE
}

extern "C" void kernel_launch(void* const* d_in, const int* in_sizes, int n_in,
                              void* d_out, int out_size, void* d_ws, size_t ws_size,
                              hipStream_t stream) {
  const float* x = (const float*)d_in[0];
  const float* W = (const float*)d_in[1];
  float* out = (float*)d_out;
  char* ws = (char*)d_ws;

  short* Wb = (short*)ws;                                   // 96 KB (pad 128K)
  short* Lx = (short*)(ws + (1 << 17));                     // 16 MB bf16 logits
  char* after = ws + (1 << 17) + (size_t)Bdim * Ndim * Kdim * 2;
  float* pm = (float*)after;                                // [32][64][64] tile max
  float* psum = pm + Bdim * 64 * 64;                        // [32][64][64] tile sum
  float* mv = psum + Bdim * 64 * 64;                        // 2048 max
  float* iv = mv + Bdim * Kdim;                             // 2048 inv-denom

  hipLaunchKernelGGL(k0_wcvt, dim3(192), dim3(256), 0, stream, W, Wb);
  hipLaunchKernelGGL(k1_logits, dim3(Bdim * 64), dim3(256), 0, stream, x, Wb, Lx, pm, psum);
  hipLaunchKernelGGL(k2b_combine, dim3(8), dim3(256), 0, stream, pm, psum, mv, iv);
  hipLaunchKernelGGL(k3_tokens, dim3(Bdim * 16), dim3(256), 0, stream, x, Lx, mv, iv, out);
}